// Round 2
// baseline (671.187 us; speedup 1.0000x reference)
//
#include <hip/hip_runtime.h>
#include <stdint.h>

// Problem constants
#define NB 64       // tokens per (b,t) group
#define DD 256      // input dim
#define HH 512      // hidden dim
#define NGROUP 2048 // B*T

typedef __attribute__((ext_vector_type(8))) _Float16 half8;
typedef __attribute__((ext_vector_type(4))) float f32x4;

__device__ __forceinline__ half8 ld8(const _Float16* p) {
    return *reinterpret_cast<const half8*>(p);
}

// ---------------- precompute kernels (unchanged, validated R1) ----------------

__global__ void prep_G_kernel(const float* __restrict__ Wq, const float* __restrict__ Wk,
                              _Float16* __restrict__ G, float scale) {
    const int d = blockIdx.x;
    const int e = threadIdx.x;
    const float4* qa = reinterpret_cast<const float4*>(Wq + d * HH);
    const float4* ka = reinterpret_cast<const float4*>(Wk + e * HH);
    float s = 0.f;
    #pragma unroll 8
    for (int j = 0; j < HH / 4; ++j) {
        float4 a = qa[j], b = ka[j];
        s += a.x * b.x + a.y * b.y + a.z * b.z + a.w * b.w;
    }
    G[d * DD + e] = (_Float16)(s * scale);
}

__global__ void prep_U_kernel(const float* __restrict__ Wv, const float* __restrict__ W1p,
                              _Float16* __restrict__ UT) {
    const int o = blockIdx.x;
    const int d = threadIdx.x;
    const float4* va = reinterpret_cast<const float4*>(Wv + d * HH);
    float s = 0.f;
    #pragma unroll 4
    for (int j4 = 0; j4 < HH / 4; ++j4) {
        float4 a = va[j4];
        const int j = j4 * 4;
        s += a.x * W1p[(j + 0) * HH + o];
        s += a.y * W1p[(j + 1) * HH + o];
        s += a.z * W1p[(j + 2) * HH + o];
        s += a.w * W1p[(j + 3) * HH + o];
    }
    UT[o * DD + d] = (_Float16)s;
}

__global__ void prep_W2T_kernel(const float* __restrict__ W2, _Float16* __restrict__ W2T) {
    __shared__ float tile[32][33];
    const int bk = blockIdx.x * 32;
    const int bh = blockIdx.y * 32;
    const int tx = threadIdx.x & 31, ty = threadIdx.x >> 5;
    #pragma unroll
    for (int i = 0; i < 32; i += 8)
        tile[ty + i][tx] = W2[(bh + ty + i) * HH + bk + tx];
    __syncthreads();
    #pragma unroll
    for (int i = 0; i < 32; i += 8)
        W2T[(bk + ty + i) * HH + bh + tx] = (_Float16)tile[tx][ty + i];
}

// ---------------- main fused kernel ----------------
// LDS (80 KiB/block -> 2 blocks/CU):
//   X1 @ 0      : [64][256] f16 swizzled (later g1)
//   X2 @ 32768  : [64][256] f16 swizzled (later g2)
//   R  @ 65536  : 16 KiB multi-use: A-chunk [64][128] | P1[64][64]+P2[64][64] | hc [64][128]
// Swizzle: byte ^= (row&7)<<4 within each row (16B-granule spread across banks).
#define LDS_X1 0
#define LDS_X2 32768
#define LDS_R  65536

__device__ __forceinline__ int swz512(int row, int bc) { return row * 512 + (bc ^ ((row & 7) << 4)); }
__device__ __forceinline__ int swz256(int row, int bc) { return row * 256 + (bc ^ ((row & 7) << 4)); }
__device__ __forceinline__ int swz128(int row, int bc) { return row * 128 + (bc ^ ((row & 7) << 4)); }

__global__ __launch_bounds__(512, 4)
void fused_kernel(const float* __restrict__ x1g, const float* __restrict__ x2g,
                  const _Float16* __restrict__ G1, const _Float16* __restrict__ G2,
                  const _Float16* __restrict__ U1T, const _Float16* __restrict__ U2T,
                  const _Float16* __restrict__ W2T,
                  const float* __restrict__ b1, const float* __restrict__ b2,
                  float* __restrict__ out) {
    __shared__ __align__(16) char lds[81920];

    const int tid = threadIdx.x;
    const int lane = tid & 63;
    const int w = tid >> 6;          // wave 0..7
    const int c = lane & 15;
    const int kg = lane >> 4;
    const size_t g = blockIdx.x;
    const f32x4 z = {0.f, 0.f, 0.f, 0.f};

    // ---- Phase 0: stage x1,x2 -> f16 swizzled LDS ----
    {
        const float4* s1 = reinterpret_cast<const float4*>(x1g) + g * (NB * DD / 4);
        const float4* s2 = reinterpret_cast<const float4*>(x2g) + g * (NB * DD / 4);
        #pragma unroll
        for (int it = 0; it < 4; ++it) {
            const int G = tid + 512 * it;       // granule id: 8 f16 each
            const int row = G >> 5;             // 32 granules per 256-f16 row
            const int cg = G & 31;
            float4 a0 = s1[row * 64 + cg * 2], a1 = s1[row * 64 + cg * 2 + 1];
            float4 b0 = s2[row * 64 + cg * 2], b1v = s2[row * 64 + cg * 2 + 1];
            half8 ha, hb;
            ha[0] = (_Float16)a0.x; ha[1] = (_Float16)a0.y; ha[2] = (_Float16)a0.z; ha[3] = (_Float16)a0.w;
            ha[4] = (_Float16)a1.x; ha[5] = (_Float16)a1.y; ha[6] = (_Float16)a1.z; ha[7] = (_Float16)a1.w;
            hb[0] = (_Float16)b0.x; hb[1] = (_Float16)b0.y; hb[2] = (_Float16)b0.z; hb[3] = (_Float16)b0.w;
            hb[4] = (_Float16)b1v.x; hb[5] = (_Float16)b1v.y; hb[6] = (_Float16)b1v.z; hb[7] = (_Float16)b1v.w;
            *reinterpret_cast<half8*>(lds + LDS_X1 + swz512(row, cg * 16)) = ha;
            *reinterpret_cast<half8*>(lds + LDS_X2 + swz512(row, cg * 16)) = hb;
        }
    }
    __syncthreads();

    // ---- Attention scores: S1 (waves 0-3) and S2 (waves 4-7) in registers ----
    // A-chunk: CH[m][d'] (128-wide) = Xsrc[m,:] . Gm[d',:]  -> LDS R
    // S partial: S[n][m] += Xq[n, chunk] . CH[m, :]^T
    f32x4 Sacc[4] = {z, z, z, z};   // 4 m-tiles; rows n = 16*(w&3)+kg*4+r, col m = 16*j+c
    const int wn = w & 3;
    for (int ai = 0; ai < 2; ++ai) {
        const _Float16* Gm = ai ? G2 : G1;
        const int xsrc = ai ? LDS_X1 : LDS_X2;   // A1 = X1.G2^T ; A2 = X2.G1^T
        const int xq   = ai ? LDS_X2 : LDS_X1;   // S2 = X2.A1^T ; S1 = X1.A2^T
        for (int ci = 0; ci < 2; ++ci) {
            // each wave computes d'-tile w (16 cols) for all 64 m
            const _Float16* gp = Gm + (size_t)(128 * ci + 16 * w + c) * DD;
            half8 bf[8];
            #pragma unroll
            for (int ks = 0; ks < 8; ++ks) bf[ks] = ld8(gp + ks * 32 + kg * 8);
            #pragma unroll
            for (int i = 0; i < 4; ++i) {
                f32x4 acc = z;
                #pragma unroll
                for (int ks = 0; ks < 8; ++ks) {
                    half8 af = *reinterpret_cast<const half8*>(lds + xsrc + swz512(16 * i + c, 64 * ks + 16 * kg));
                    acc = __builtin_amdgcn_mfma_f32_16x16x32_f16(af, bf[ks], acc, 0, 0, 0);
                }
                #pragma unroll
                for (int r = 0; r < 4; ++r)
                    *reinterpret_cast<_Float16*>(lds + LDS_R + swz256(16 * i + kg * 4 + r, 2 * (16 * w + c))) = (_Float16)acc[r];
            }
            __syncthreads();
            if ((w >> 2) == ai) {
                #pragma unroll
                for (int ks = 0; ks < 4; ++ks) {
                    half8 af = *reinterpret_cast<const half8*>(lds + xq + swz512(16 * wn + c, 256 * ci + 64 * ks + 16 * kg));
                    #pragma unroll
                    for (int j = 0; j < 4; ++j) {
                        half8 bfr = *reinterpret_cast<const half8*>(lds + LDS_R + swz256(16 * j + c, 64 * ks + 16 * kg));
                        Sacc[j] = __builtin_amdgcn_mfma_f32_16x16x32_f16(af, bfr, Sacc[j], 0, 0, 0);
                    }
                }
            }
            __syncthreads();
        }
    }

    // ---- In-register row softmax -> P (f16, LDS R). waves 0-3 -> P1, 4-7 -> P2 ----
    {
        const int Pb = LDS_R + ((w < 4) ? 0 : 8192);
        #pragma unroll
        for (int r = 0; r < 4; ++r) {
            float m0 = fmaxf(fmaxf(Sacc[0][r], Sacc[1][r]), fmaxf(Sacc[2][r], Sacc[3][r]));
            m0 = fmaxf(m0, __shfl_xor(m0, 1));
            m0 = fmaxf(m0, __shfl_xor(m0, 2));
            m0 = fmaxf(m0, __shfl_xor(m0, 4));
            m0 = fmaxf(m0, __shfl_xor(m0, 8));
            float e0 = __expf(Sacc[0][r] - m0);
            float e1 = __expf(Sacc[1][r] - m0);
            float e2 = __expf(Sacc[2][r] - m0);
            float e3 = __expf(Sacc[3][r] - m0);
            float s0 = e0 + e1 + e2 + e3;
            s0 += __shfl_xor(s0, 1);
            s0 += __shfl_xor(s0, 2);
            s0 += __shfl_xor(s0, 4);
            s0 += __shfl_xor(s0, 8);
            const float inv = 1.f / s0;
            const int row = 16 * wn + kg * 4 + r;
            *reinterpret_cast<_Float16*>(lds + Pb + swz128(row, 2 * (16 * 0 + c))) = (_Float16)(e0 * inv);
            *reinterpret_cast<_Float16*>(lds + Pb + swz128(row, 2 * (16 * 1 + c))) = (_Float16)(e1 * inv);
            *reinterpret_cast<_Float16*>(lds + Pb + swz128(row, 2 * (16 * 2 + c))) = (_Float16)(e2 * inv);
            *reinterpret_cast<_Float16*>(lds + Pb + swz128(row, 2 * (16 * 3 + c))) = (_Float16)(e3 * inv);
        }
    }
    __syncthreads();

    // ---- g = P @ X  (B-fragments = X^T via strided b16 LDS reads) ----
    // waves 0-3: g1 rows 16*wn (P1, X1); waves 4-7: g2 rows 16*wn (P2, X2)
    {
        f32x4 gacc[16];
        #pragma unroll
        for (int t = 0; t < 16; ++t) gacc[t] = z;
        const int Pb = LDS_R + ((w < 4) ? 0 : 8192);
        const int xg = (w < 4) ? LDS_X1 : LDS_X2;
        #pragma unroll
        for (int ks = 0; ks < 2; ++ks) {
            half8 af = *reinterpret_cast<const half8*>(lds + Pb + swz128(16 * wn + c, 64 * ks + 16 * kg));
            #pragma unroll
            for (int t = 0; t < 16; ++t) {
                half8 bfr;
                #pragma unroll
                for (int jj = 0; jj < 8; ++jj) {
                    const int m = 32 * ks + kg * 8 + jj;
                    bfr[jj] = *reinterpret_cast<const _Float16*>(lds + xg + swz512(m, 2 * (16 * t + c)));
                }
                gacc[t] = __builtin_amdgcn_mfma_f32_16x16x32_f16(af, bfr, gacc[t], 0, 0, 0);
            }
        }
        __syncthreads();   // all reads of X1/X2/P done
        #pragma unroll
        for (int t = 0; t < 16; ++t)
            #pragma unroll
            for (int r = 0; r < 4; ++r)
                *reinterpret_cast<_Float16*>(lds + xg + swz512(16 * wn + kg * 4 + r, 2 * (16 * t + c))) = (_Float16)gacc[t][r];
    }
    __syncthreads();

    // ---- Fused MLP: out[64x512] acc in regs; h streamed in 128-col chunks via LDS R ----
    f32x4 oacc[4][4];
    #pragma unroll
    for (int i = 0; i < 4; ++i)
        #pragma unroll
        for (int j = 0; j < 4; ++j) oacc[i][j] = z;

    for (int q = 0; q < 4; ++q) {
        // hc[:, 16*w + c] = relu(g . U[:, hcol] + b1)  (each wave owns 16 cols of the chunk)
        f32x4 hacc[4] = {z, z, z, z};
        #pragma unroll
        for (int hf = 0; hf < 2; ++hf) {
            const _Float16* UT = hf ? U2T : U1T;
            const int gb = hf ? LDS_X2 : LDS_X1;
            const _Float16* up = UT + (size_t)(128 * q + 16 * w + c) * DD;
            #pragma unroll
            for (int ks = 0; ks < 8; ++ks) {
                half8 bfr = ld8(up + ks * 32 + kg * 8);
                #pragma unroll
                for (int i = 0; i < 4; ++i) {
                    half8 af = *reinterpret_cast<const half8*>(lds + gb + swz512(16 * i + c, 64 * ks + 16 * kg));
                    hacc[i] = __builtin_amdgcn_mfma_f32_16x16x32_f16(af, bfr, hacc[i], 0, 0, 0);
                }
            }
        }
        const float bb = b1[128 * q + 16 * w + c];
        #pragma unroll
        for (int i = 0; i < 4; ++i)
            #pragma unroll
            for (int r = 0; r < 4; ++r)
                *reinterpret_cast<_Float16*>(lds + LDS_R + swz256(16 * i + kg * 4 + r, 2 * (16 * w + c))) =
                    (_Float16)fmaxf(hacc[i][r] + bb, 0.f);
        __syncthreads();
        // out[:, 64w..64w+64] += hc . W2T[ocol, chunk]^T
        #pragma unroll
        for (int ks = 0; ks < 4; ++ks) {
            half8 af[4];
            #pragma unroll
            for (int i = 0; i < 4; ++i)
                af[i] = *reinterpret_cast<const half8*>(lds + LDS_R + swz256(16 * i + c, 64 * ks + 16 * kg));
            #pragma unroll
            for (int j = 0; j < 4; ++j) {
                half8 bfr = ld8(W2T + (size_t)(64 * w + 16 * j + c) * HH + 128 * q + 32 * ks + kg * 8);
                #pragma unroll
                for (int i = 0; i < 4; ++i)
                    oacc[i][j] = __builtin_amdgcn_mfma_f32_16x16x32_f16(af[i], bfr, oacc[i][j], 0, 0, 0);
            }
        }
        __syncthreads();   // hc free for next chunk
    }

    // ---- Epilogue: out + b2 ----
    float* og = out + g * (size_t)(NB * HH);
    #pragma unroll
    for (int j = 0; j < 4; ++j) {
        const float b2v = b2[64 * w + 16 * j + c];
        #pragma unroll
        for (int i = 0; i < 4; ++i) {
            const int r0 = 16 * i + kg * 4;
            #pragma unroll
            for (int r = 0; r < 4; ++r)
                og[(size_t)(r0 + r) * HH + 64 * w + 16 * j + c] = oacc[i][j][r] + b2v;
        }
    }
}

// ---------------- launch ----------------

extern "C" void kernel_launch(void* const* d_in, const int* in_sizes, int n_in,
                              void* d_out, int out_size, void* d_ws, size_t ws_size,
                              hipStream_t stream) {
    (void)in_sizes; (void)n_in; (void)out_size; (void)ws_size;
    const float* x1  = (const float*)d_in[0];
    const float* x2  = (const float*)d_in[1];
    const float* Wq1 = (const float*)d_in[2];
    const float* Wk1 = (const float*)d_in[3];
    const float* Wv1 = (const float*)d_in[4];
    const float* Wq2 = (const float*)d_in[5];
    const float* Wk2 = (const float*)d_in[6];
    const float* Wv2 = (const float*)d_in[7];
    const float* W1  = (const float*)d_in[8];
    const float* b1  = (const float*)d_in[9];
    const float* W2  = (const float*)d_in[10];
    const float* b2  = (const float*)d_in[11];
    float* out = (float*)d_out;

    char* ws = (char*)d_ws;
    _Float16* G1  = (_Float16*)(ws + 0);
    _Float16* G2  = (_Float16*)(ws + 131072);
    _Float16* U1T = (_Float16*)(ws + 262144);
    _Float16* U2T = (_Float16*)(ws + 524288);
    _Float16* W2T = (_Float16*)(ws + 786432);

    const float scale = 0.0625f;  // D^-0.5

    prep_G_kernel<<<DD, DD, 0, stream>>>(Wq1, Wk2, G1, scale);
    prep_G_kernel<<<DD, DD, 0, stream>>>(Wq2, Wk1, G2, scale);
    prep_U_kernel<<<HH, DD, 0, stream>>>(Wv1, W1, U1T);
    prep_U_kernel<<<HH, DD, 0, stream>>>(Wv2, W1 + HH * HH, U2T);
    prep_W2T_kernel<<<dim3(16, 16), 256, 0, stream>>>(W2, W2T);

    fused_kernel<<<NGROUP, 512, 0, stream>>>(x1, x2, G1, G2, U1T, U2T, W2T, b1, b2, out);
}